// Round 5
// baseline (530.222 us; speedup 1.0000x reference)
//
#include <hip/hip_runtime.h>
#include <cmath>

#define NN 100000
#define NP 100096             // NN rounded up to 128 (GEMM M-tile, avoids tail predication)
#define EE 400000
#define ET (EE + NN)          // 500000 edges incl. self-loops
#define SLOPE 0.2f

typedef __attribute__((ext_vector_type(8))) short short8;
typedef __attribute__((ext_vector_type(4))) float floatx4;

__device__ __forceinline__ float b2f(ushort u) {
    union { unsigned int i; float f; } v; v.i = ((unsigned int)u) << 16; return v.f;
}
__device__ __forceinline__ ushort f2b(float f) {
    union { float f; unsigned int i; } v; v.f = f;
    unsigned int r = v.i + 0x7FFFu + ((v.i >> 16) & 1u);   // RNE
    return (ushort)(r >> 16);
}

// async global->LDS, 16B per lane, dst = wave-uniform base + lane*16
#define GLL16(g, l) __builtin_amdgcn_global_load_lds( \
    (const __attribute__((address_space(1))) unsigned int*)(g), \
    (__attribute__((address_space(3))) unsigned int*)(l), 16, 0, 0)

// ---------------------------------------------------------------- CSR build
__global__ __launch_bounds__(256) void count_deg(const int* __restrict__ ei, int* __restrict__ deg) {
    int e = blockIdx.x * 256 + threadIdx.x;
    if (e < EE) atomicAdd(&deg[ei[EE + e]], 1);
}

__global__ __launch_bounds__(256) void scan1(const int* __restrict__ deg, int* __restrict__ incl,
                                             int* __restrict__ bsums) {
    __shared__ int ts[256];
    int b = blockIdx.x, t = threadIdx.x;
    int base = b * 1024 + t * 4;
    int v[4];
#pragma unroll
    for (int i = 0; i < 4; i++) {
        int n = base + i;
        v[i] = (n < NN) ? (deg[n] + 1) : 0;
    }
    int s = 0;
#pragma unroll
    for (int i = 0; i < 4; i++) { s += v[i]; v[i] = s; }
    ts[t] = s;
    __syncthreads();
    for (int off = 1; off < 256; off <<= 1) {
        int x = (t >= off) ? ts[t - off] : 0;
        __syncthreads();
        ts[t] += x;
        __syncthreads();
    }
    int excl = ts[t] - s;
#pragma unroll
    for (int i = 0; i < 4; i++) {
        int n = base + i;
        if (n < NN) incl[n] = v[i] + excl;
    }
    if (t == 255) bsums[b] = ts[255];
}

__global__ __launch_bounds__(128) void scan2(int* __restrict__ bsums, int nblk) {
    __shared__ int ts[128];
    int t = threadIdx.x;
    int v = (t < nblk) ? bsums[t] : 0;
    ts[t] = v;
    __syncthreads();
    for (int off = 1; off < 128; off <<= 1) {
        int x = (t >= off) ? ts[t - off] : 0;
        __syncthreads();
        ts[t] += x;
        __syncthreads();
    }
    if (t < nblk) bsums[t] = ts[t] - v;
}

__global__ __launch_bounds__(256) void scan3(const int* __restrict__ incl, const int* __restrict__ deg,
                                             const int* __restrict__ bsums, int* __restrict__ row_ptr,
                                             int* __restrict__ cursor) {
    int n = blockIdx.x * 256 + threadIdx.x;
    if (n < NN) {
        int rp = incl[n] - (deg[n] + 1) + bsums[n >> 10];
        row_ptr[n] = rp;
        cursor[n] = rp;
    }
    if (n == 0) row_ptr[NN] = ET;
}

__global__ __launch_bounds__(256) void scatter(const int* __restrict__ ei, int* __restrict__ cursor,
                                               int* __restrict__ col) {
    int e = blockIdx.x * 256 + threadIdx.x;
    if (e < EE) {
        int d = ei[EE + e];
        int p = atomicAdd(&cursor[d], 1);
        col[p] = ei[e];
    }
}

__global__ __launch_bounds__(256) void selfloop(const int* __restrict__ cursor, int* __restrict__ col) {
    int n = blockIdx.x * 256 + threadIdx.x;
    if (n < NN) col[cursor[n]] = n;
}

// ---------------------------------------------------------------- casts
__global__ __launch_bounds__(256) void cast_to_bf16(const float* __restrict__ in,
                                                    ushort* __restrict__ out, int n4) {
    int i = blockIdx.x * 256 + threadIdx.x;
    if (i < n4) {
        float4 v = ((const float4*)in)[i];
        ushort4 o;
        o.x = f2b(v.x); o.y = f2b(v.y); o.z = f2b(v.z); o.w = f2b(v.w);
        ((ushort4*)out)[i] = o;
    }
}

// Wt[n*K + k] = bf16(W[k*N + n])
__global__ __launch_bounds__(256) void transpose_cast(const float* __restrict__ W,
                                                      ushort* __restrict__ Wt, int K, int N) {
    int idx = blockIdx.x * 256 + threadIdx.x;
    if (idx < N * K) {
        int n = idx / K, k = idx % K;
        Wt[idx] = f2b(W[(size_t)k * N + n]);
    }
}

// ---------------------------------------------------------------- bf16 MFMA GEMM + fused scores
// C[M,N] bf16 = A[M,K] @ Bt[N,K]^T, fp32 accum. Tile 128x128, BK=32, 4 waves (2x2).
// LDS in FRAGMENT ORDER: sub-tile s (16 rows x 32 k) at s*1024B, lane's 8 bf16 at lane*16B.
// global_load_lds stages straight into that layout (wave-uniform base + lane*16).
// Epilogue: per-wave col-block == one head (C=64 or 128) -> reduce h·a_src / h·a_dst
// from acc regs, atomicAdd into als/ald (pre-zeroed).
__global__ __launch_bounds__(256) void gemm_bf16(const ushort* __restrict__ A,
                                                 const ushort* __restrict__ Bt,
                                                 ushort* __restrict__ C,
                                                 const float* __restrict__ a_s,
                                                 const float* __restrict__ a_d,
                                                 float* __restrict__ als,
                                                 float* __restrict__ ald,
                                                 int M, int K, int N, int H) {
    __shared__ ushort As[8 * 512];   // 8 KB
    __shared__ ushort Bs[8 * 512];   // 8 KB
    int tid = threadIdx.x;
    int wave = tid >> 6, lane = tid & 63;
    int bm = blockIdx.x * 128, bn = blockIdx.y * 128;
    int wm = (wave >> 1) * 64, wn = (wave & 1) * 64;
    int frow = lane & 15, kq = (lane >> 4) * 8;

    floatx4 acc[4][4];
#pragma unroll
    for (int i = 0; i < 4; i++)
#pragma unroll
        for (int j = 0; j < 4; j++) acc[i][j] = (floatx4)0.f;

    // staging: wave w loads A sub-tiles {2w,2w+1} and B sub-tiles {2w,2w+1}
    int s0 = wave * 2;
    const ushort* gA0 = A + (size_t)(bm + s0 * 16 + frow) * K + kq;
    const ushort* gA1 = gA0 + (size_t)16 * K;
    const ushort* gB0 = Bt + (size_t)(bn + s0 * 16 + frow) * K + kq;
    const ushort* gB1 = gB0 + (size_t)16 * K;
    ushort* lA0 = As + s0 * 512;
    ushort* lA1 = As + (s0 + 1) * 512;
    ushort* lB0 = Bs + s0 * 512;
    ushort* lB1 = Bs + (s0 + 1) * 512;

    int sa = wm >> 4;   // wave's first A sub-tile index
    int sb = wn >> 4;   // wave's first B sub-tile index

    for (int k0 = 0; k0 < K; k0 += 32) {
        GLL16(gA0 + k0, lA0);
        GLL16(gA1 + k0, lA1);
        GLL16(gB0 + k0, lB0);
        GLL16(gB1 + k0, lB1);
        __syncthreads();   // drains vmcnt (global_load_lds) + barrier

        short8 afr[4], bfr[4];
#pragma unroll
        for (int i = 0; i < 4; i++)
            afr[i] = *(const short8*)&As[(sa + i) * 512 + lane * 8];
#pragma unroll
        for (int j = 0; j < 4; j++)
            bfr[j] = *(const short8*)&Bs[(sb + j) * 512 + lane * 8];
#pragma unroll
        for (int i = 0; i < 4; i++)
#pragma unroll
            for (int j = 0; j < 4; j++)
                acc[i][j] = __builtin_amdgcn_mfma_f32_16x16x32_bf16(afr[i], bfr[j], acc[i][j], 0, 0, 0);

        __syncthreads();   // protect LDS before next stage
    }

    // ---- C write: row = quad*4+reg, col = lane&15 (verified m89 mapping)
    int ccol = bn + wn + frow;
    int crow = bm + wm + (lane >> 4) * 4;
#pragma unroll
    for (int i = 0; i < 4; i++) {
#pragma unroll
        for (int reg = 0; reg < 4; reg++) {
            int row = crow + i * 16 + reg;
            if (row < M) {
#pragma unroll
                for (int j = 0; j < 4; j++)
                    C[(size_t)row * N + ccol + j * 16] = f2b(acc[i][j][reg]);
            }
        }
    }

    // ---- fused attention scores: this wave's 64 cols lie in exactly one head
    int Cc = N / H;                 // channels per head (64 or 128)
    int hd = (bn + wn) / Cc;
    float avs[4], avd[4];
#pragma unroll
    for (int j = 0; j < 4; j++) {
        avs[j] = a_s[bn + wn + frow + j * 16];
        avd[j] = a_d[bn + wn + frow + j * 16];
    }
#pragma unroll
    for (int i = 0; i < 4; i++) {
#pragma unroll
        for (int reg = 0; reg < 4; reg++) {
            float ps = 0.f, pd = 0.f;
#pragma unroll
            for (int j = 0; j < 4; j++) {
                float v = acc[i][j][reg];
                ps += v * avs[j];
                pd += v * avd[j];
            }
            // reduce over the 16 lanes (col dim) sharing this row
#pragma unroll
            for (int off = 1; off < 16; off <<= 1) {
                ps += __shfl_xor(ps, off, 64);
                pd += __shfl_xor(pd, off, 64);
            }
            int row = crow + i * 16 + reg;
            if ((lane & 15) == 0 && row < M) {
                atomicAdd(&als[row * H + hd], ps);
                atomicAdd(&ald[row * H + hd], pd);
            }
        }
    }
}

// ---------------------------------------------------------------- CSR aggregation
// ONE WAVE PER DST NODE, all heads together.
template <int H, int HC, bool ELU_ACT, bool OUT_BF16>
__global__ __launch_bounds__(256) void aggregate(const ushort* __restrict__ hlin,
                                                 const float* __restrict__ als,
                                                 const float* __restrict__ ald,
                                                 const int* __restrict__ row_ptr,
                                                 const int* __restrict__ col,
                                                 const float* __restrict__ bias,
                                                 void* __restrict__ outv) {
    constexpr int CP = HC / 64;       // channels per lane (4 or 2)
    constexpr int GS = 64 / H;        // lanes per head group (16 or 64)
    int wv = threadIdx.x >> 6, lane = threadIdx.x & 63;
    int dst = blockIdx.x * 4 + wv;
    if (dst >= NN) return;
    int rs = row_ptr[dst], re = row_ptr[dst + 1];
    int deg = re - rs;
    int eg = lane & (GS - 1);
    int head = lane / GS;
    float ad = ald[dst * H + head];

    float acc[CP];
#pragma unroll
    for (int j = 0; j < CP; j++) acc[j] = 0.f;

    uint laneoff = (uint)(lane * CP);

    if (deg <= GS) {
        int src = 0;
        float s = -1e30f;
        if (eg < deg) {
            src = col[rs + eg];
            float sc = als[src * H + head] + ad;
            s = sc > 0.f ? sc : SLOPE * sc;
        }
        float m = s;
#pragma unroll
        for (int off = 1; off < GS; off <<= 1) m = fmaxf(m, __shfl_xor(m, off, 64));
        float e = (eg < deg) ? __expf(s - m) : 0.f;
        float sum = e;
#pragma unroll
        for (int off = 1; off < GS; off <<= 1) sum += __shfl_xor(sum, off, 64);
        float w = e * (1.0f / (sum + 1e-16f));

        int hbase = head * GS;
        int d = 0;
        for (; d + 4 <= deg; d += 4) {
            int s0 = __shfl(src, d, 64),     s1 = __shfl(src, d + 1, 64);
            int s2 = __shfl(src, d + 2, 64), s3 = __shfl(src, d + 3, 64);
            float w0 = __shfl(w, hbase + d, 64),     w1 = __shfl(w, hbase + d + 1, 64);
            float w2 = __shfl(w, hbase + d + 2, 64), w3 = __shfl(w, hbase + d + 3, 64);
            const uint* p0 = (const uint*)(hlin + (uint)s0 * HC + laneoff);
            const uint* p1 = (const uint*)(hlin + (uint)s1 * HC + laneoff);
            const uint* p2 = (const uint*)(hlin + (uint)s2 * HC + laneoff);
            const uint* p3 = (const uint*)(hlin + (uint)s3 * HC + laneoff);
            uint u0[CP / 2], u1[CP / 2], u2[CP / 2], u3[CP / 2];
#pragma unroll
            for (int q = 0; q < CP / 2; q++) { u0[q] = p0[q]; u1[q] = p1[q]; u2[q] = p2[q]; u3[q] = p3[q]; }
#pragma unroll
            for (int q = 0; q < CP / 2; q++) {
                acc[2*q]   += w0 * b2f((ushort)(u0[q] & 0xffff)) + w1 * b2f((ushort)(u1[q] & 0xffff))
                            + w2 * b2f((ushort)(u2[q] & 0xffff)) + w3 * b2f((ushort)(u3[q] & 0xffff));
                acc[2*q+1] += w0 * b2f((ushort)(u0[q] >> 16)) + w1 * b2f((ushort)(u1[q] >> 16))
                            + w2 * b2f((ushort)(u2[q] >> 16)) + w3 * b2f((ushort)(u3[q] >> 16));
            }
        }
        for (; d < deg; d++) {
            int sd = __shfl(src, d, 64);
            float wd = __shfl(w, hbase + d, 64);
            const uint* p = (const uint*)(hlin + (uint)sd * HC + laneoff);
#pragma unroll
            for (int q = 0; q < CP / 2; q++) {
                uint u = p[q];
                acc[2*q]   += wd * b2f((ushort)(u & 0xffff));
                acc[2*q+1] += wd * b2f((ushort)(u >> 16));
            }
        }
    } else {
        float m = -1e30f;
        for (int e2 = eg; e2 < deg; e2 += GS) {
            int sc0 = col[rs + e2];
            float sc = als[sc0 * H + head] + ad;
            sc = sc > 0.f ? sc : SLOPE * sc;
            m = fmaxf(m, sc);
        }
#pragma unroll
        for (int off = 1; off < GS; off <<= 1) m = fmaxf(m, __shfl_xor(m, off, 64));
        float sum = 0.f;
        for (int e2 = eg; e2 < deg; e2 += GS) {
            int sc0 = col[rs + e2];
            float sc = als[sc0 * H + head] + ad;
            sc = sc > 0.f ? sc : SLOPE * sc;
            sum += __expf(sc - m);
        }
#pragma unroll
        for (int off = 1; off < GS; off <<= 1) sum += __shfl_xor(sum, off, 64);
        float inv = 1.0f / (sum + 1e-16f);
        for (int d = 0; d < deg; d++) {
            int sd = col[rs + d];
            float sc = als[sd * H + head] + ad;
            sc = sc > 0.f ? sc : SLOPE * sc;
            float wd = __expf(sc - m) * inv;
            const uint* p = (const uint*)(hlin + (uint)sd * HC + laneoff);
#pragma unroll
            for (int q = 0; q < CP / 2; q++) {
                uint u = p[q];
                acc[2*q]   += wd * b2f((ushort)(u & 0xffff));
                acc[2*q+1] += wd * b2f((ushort)(u >> 16));
            }
        }
    }

#pragma unroll
    for (int j = 0; j < CP; j++) {
        float v = acc[j] + bias[lane * CP + j];
        if (ELU_ACT) v = v > 0.f ? v : (__expf(v) - 1.0f);
        acc[j] = v;
    }
    if (OUT_BF16) {
        ushort* outp = (ushort*)outv + (size_t)dst * HC + laneoff;
        uint pk[CP / 2];
#pragma unroll
        for (int q = 0; q < CP / 2; q++)
            pk[q] = (uint)f2b(acc[2*q]) | ((uint)f2b(acc[2*q+1]) << 16);
#pragma unroll
        for (int q = 0; q < CP / 2; q++) ((uint*)outp)[q] = pk[q];
    } else {
        float* outp = (float*)outv + (size_t)dst * HC + laneoff;
#pragma unroll
        for (int j = 0; j < CP; j++) outp[j] = acc[j];
    }
}

// ---------------------------------------------------------------- launch
extern "C" void kernel_launch(void* const* d_in, const int* in_sizes, int n_in,
                              void* d_out, int out_size, void* d_ws, size_t ws_size,
                              hipStream_t stream) {
    const float* x   = (const float*)d_in[0];
    const int*   ei  = (const int*)d_in[1];
    const float* W0  = (const float*)d_in[2];
    const float* as0 = (const float*)d_in[3];
    const float* ad0 = (const float*)d_in[4];
    const float* b0  = (const float*)d_in[5];
    const float* W1  = (const float*)d_in[6];
    const float* as1 = (const float*)d_in[7];
    const float* ad1 = (const float*)d_in[8];
    const float* b1  = (const float*)d_in[9];
    const float* W2  = (const float*)d_in[10];
    const float* as2 = (const float*)d_in[11];
    const float* ad2 = (const float*)d_in[12];
    const float* b2  = (const float*)d_in[13];
    float* out = (float*)d_out;

    char* ws = (char*)d_ws;
    size_t off = 0;
    auto alloc = [&](size_t bytes) {
        void* p = ws + off;
        off += (bytes + 255) & ~(size_t)255;
        return p;
    };
    ushort* xb   = (ushort*)alloc((size_t)NP * 128 * 2);   // padded to NP rows
    ushort* h    = (ushort*)alloc((size_t)NP * 256 * 2);
    ushort* actB = (ushort*)alloc((size_t)NP * 256 * 2);
    ushort* actC = (ushort*)alloc((size_t)NP * 256 * 2);
    ushort* Wt0  = (ushort*)alloc((size_t)256 * 128 * 2);
    ushort* Wt1  = (ushort*)alloc((size_t)256 * 256 * 2);
    ushort* Wt2  = (ushort*)alloc((size_t)128 * 256 * 2);
    float* als   = (float*)alloc((size_t)NN * 4 * 4);
    float* ald   = (float*)alloc((size_t)NN * 4 * 4);
    int* deg     = (int*)alloc((size_t)NN * 4);
    int* incl    = (int*)alloc((size_t)NN * 4);
    int* row_ptr = (int*)alloc((size_t)(NN + 1) * 4);
    int* cursor  = (int*)alloc((size_t)NN * 4);
    int* col     = (int*)alloc((size_t)ET * 4);
    int* bsums   = (int*)alloc(128 * 4);

    const int NBLK = (NN + 1023) / 1024;   // 98

    // ---- CSR (shared by all layers)
    hipMemsetAsync(deg, 0, (size_t)NN * 4, stream);
    count_deg<<<(EE + 255) / 256, 256, 0, stream>>>(ei, deg);
    scan1<<<NBLK, 256, 0, stream>>>(deg, incl, bsums);
    scan2<<<1, 128, 0, stream>>>(bsums, NBLK);
    scan3<<<(NN + 255) / 256, 256, 0, stream>>>(incl, deg, bsums, row_ptr, cursor);
    scatter<<<(EE + 255) / 256, 256, 0, stream>>>(ei, cursor, col);
    selfloop<<<(NN + 255) / 256, 256, 0, stream>>>(cursor, col);

    // ---- bf16 conversions
    cast_to_bf16<<<(NN * 128 / 4 + 255) / 256, 256, 0, stream>>>(x, xb, NN * 128 / 4);
    transpose_cast<<<(256 * 128 + 255) / 256, 256, 0, stream>>>(W0, Wt0, 128, 256);
    transpose_cast<<<(256 * 256 + 255) / 256, 256, 0, stream>>>(W1, Wt1, 256, 256);
    transpose_cast<<<(128 * 256 + 255) / 256, 256, 0, stream>>>(W2, Wt2, 256, 128);

    const int GM = NP / 128;           // 782
    const int NB4 = (NN + 3) / 4;      // 25000
    const size_t ALB = (size_t)NN * 4 * 4;

    // ---- layer 0
    hipMemsetAsync(als, 0, ALB, stream);
    hipMemsetAsync(ald, 0, ALB, stream);
    gemm_bf16<<<dim3(GM, 2), 256, 0, stream>>>(xb, Wt0, h, as0, ad0, als, ald, NN, 128, 256, 4);
    aggregate<4, 256, true, true><<<NB4, 256, 0, stream>>>(h, als, ald, row_ptr, col, b0, actB);

    // ---- layer 1
    hipMemsetAsync(als, 0, ALB, stream);
    hipMemsetAsync(ald, 0, ALB, stream);
    gemm_bf16<<<dim3(GM, 2), 256, 0, stream>>>(actB, Wt1, h, as1, ad1, als, ald, NN, 256, 256, 4);
    aggregate<4, 256, true, true><<<NB4, 256, 0, stream>>>(h, als, ald, row_ptr, col, b1, actC);

    // ---- layer 2
    hipMemsetAsync(als, 0, ALB, stream);
    hipMemsetAsync(ald, 0, ALB, stream);
    gemm_bf16<<<dim3(GM, 1), 256, 0, stream>>>(actC, Wt2, h, as2, ad2, als, ald, NN, 256, 128, 1);
    aggregate<1, 128, false, false><<<NB4, 256, 0, stream>>>(h, als, ald, row_ptr, col, b2, out);
}

// Round 6
// 510.233 us; speedup vs baseline: 1.0392x; 1.0392x over previous
//
#include <hip/hip_runtime.h>
#include <cmath>

#define NN 100000
#define NP 100096             // NN rounded up to 128 (GEMM M-tile, no tail predication)
#define EE 400000
#define ET (EE + NN)          // 500000 edges incl. self-loops
#define SLOPE 0.2f

typedef __attribute__((ext_vector_type(8))) short short8;
typedef __attribute__((ext_vector_type(4))) float floatx4;

__device__ __forceinline__ float b2f(ushort u) {
    union { unsigned int i; float f; } v; v.i = ((unsigned int)u) << 16; return v.f;
}
__device__ __forceinline__ ushort f2b(float f) {
    union { float f; unsigned int i; } v; v.f = f;
    unsigned int r = v.i + 0x7FFFu + ((v.i >> 16) & 1u);   // RNE
    return (ushort)(r >> 16);
}

// ---------------------------------------------------------------- CSR build
__global__ __launch_bounds__(256) void count_deg(const int* __restrict__ ei, int* __restrict__ deg) {
    int e = blockIdx.x * 256 + threadIdx.x;
    if (e < EE) atomicAdd(&deg[ei[EE + e]], 1);
}

__global__ __launch_bounds__(256) void scan1(const int* __restrict__ deg, int* __restrict__ incl,
                                             int* __restrict__ bsums) {
    __shared__ int ts[256];
    int b = blockIdx.x, t = threadIdx.x;
    int base = b * 1024 + t * 4;
    int v[4];
#pragma unroll
    for (int i = 0; i < 4; i++) {
        int n = base + i;
        v[i] = (n < NN) ? (deg[n] + 1) : 0;
    }
    int s = 0;
#pragma unroll
    for (int i = 0; i < 4; i++) { s += v[i]; v[i] = s; }
    ts[t] = s;
    __syncthreads();
    for (int off = 1; off < 256; off <<= 1) {
        int x = (t >= off) ? ts[t - off] : 0;
        __syncthreads();
        ts[t] += x;
        __syncthreads();
    }
    int excl = ts[t] - s;
#pragma unroll
    for (int i = 0; i < 4; i++) {
        int n = base + i;
        if (n < NN) incl[n] = v[i] + excl;
    }
    if (t == 255) bsums[b] = ts[255];
}

__global__ __launch_bounds__(128) void scan2(int* __restrict__ bsums, int nblk) {
    __shared__ int ts[128];
    int t = threadIdx.x;
    int v = (t < nblk) ? bsums[t] : 0;
    ts[t] = v;
    __syncthreads();
    for (int off = 1; off < 128; off <<= 1) {
        int x = (t >= off) ? ts[t - off] : 0;
        __syncthreads();
        ts[t] += x;
        __syncthreads();
    }
    if (t < nblk) bsums[t] = ts[t] - v;
}

__global__ __launch_bounds__(256) void scan3(const int* __restrict__ incl, const int* __restrict__ deg,
                                             const int* __restrict__ bsums, int* __restrict__ row_ptr,
                                             int* __restrict__ cursor) {
    int n = blockIdx.x * 256 + threadIdx.x;
    if (n < NN) {
        int rp = incl[n] - (deg[n] + 1) + bsums[n >> 10];
        row_ptr[n] = rp;
        cursor[n] = rp;
    }
    if (n == 0) row_ptr[NN] = ET;
}

__global__ __launch_bounds__(256) void scatter(const int* __restrict__ ei, int* __restrict__ cursor,
                                               int* __restrict__ col) {
    int e = blockIdx.x * 256 + threadIdx.x;
    if (e < EE) {
        int d = ei[EE + e];
        int p = atomicAdd(&cursor[d], 1);
        col[p] = ei[e];
    }
}

__global__ __launch_bounds__(256) void selfloop(const int* __restrict__ cursor, int* __restrict__ col) {
    int n = blockIdx.x * 256 + threadIdx.x;
    if (n < NN) col[cursor[n]] = n;
}

// ---------------------------------------------------------------- casts
__global__ __launch_bounds__(256) void cast_to_bf16(const float* __restrict__ in,
                                                    ushort* __restrict__ out, int n4) {
    int i = blockIdx.x * 256 + threadIdx.x;
    if (i < n4) {
        float4 v = ((const float4*)in)[i];
        ushort4 o;
        o.x = f2b(v.x); o.y = f2b(v.y); o.z = f2b(v.z); o.w = f2b(v.w);
        ((ushort4*)out)[i] = o;
    }
}

// Wt[n*K + k] = bf16(W[k*N + n])
__global__ __launch_bounds__(256) void transpose_cast(const float* __restrict__ W,
                                                      ushort* __restrict__ Wt, int K, int N) {
    int idx = blockIdx.x * 256 + threadIdx.x;
    if (idx < N * K) {
        int n = idx / K, k = idx % K;
        Wt[idx] = f2b(W[(size_t)k * N + n]);
    }
}

// ---------------------------------------------------------------- bf16 MFMA GEMM + fused scores
// C[M,N] bf16 = A[M,K] @ Bt[N,K]^T, fp32 accum. Tile 128x128, BK=32, 4 waves (2x2).
// Register-path staging with EXPLICIT prefetch: iter k+1's global loads issue
// right after the first barrier, in flight under the MFMA loop + second barrier.
// (R5 lesson: global_load_lds + single buffer exposes full load latency per
// K-step because __syncthreads drains vmcnt(0) — 80 µs vs ~45 µs this way.)
// Epilogue: per-wave 64-col block == one head -> reduce h·a_src / h·a_dst from
// acc regs, atomicAdd into als/ald (pre-zeroed). A/C buffers padded to NP rows.
#define LP 40   // LDS row pitch in bf16 elems (80 B, 16B-aligned)
__global__ __launch_bounds__(256) void gemm_bf16(const ushort* __restrict__ A,
                                                 const ushort* __restrict__ Bt,
                                                 ushort* __restrict__ C,
                                                 const float* __restrict__ a_s,
                                                 const float* __restrict__ a_d,
                                                 float* __restrict__ als,
                                                 float* __restrict__ ald,
                                                 int K, int N, int H) {
    __shared__ ushort As[128 * LP];
    __shared__ ushort Bs[128 * LP];
    int tid = threadIdx.x;
    int bm = blockIdx.x * 128, bn = blockIdx.y * 128;
    int wave = tid >> 6, lane = tid & 63;
    int wm = (wave >> 1) * 64, wn = (wave & 1) * 64;
    int r = tid >> 1;            // staging row 0..127
    int c = (tid & 1) * 16;      // col half: 0 or 16
    int frow = lane & 15, kq = (lane >> 4) * 8;

    floatx4 acc[4][4];
#pragma unroll
    for (int i = 0; i < 4; i++)
#pragma unroll
        for (int j = 0; j < 4; j++) acc[i][j] = (floatx4)0.f;

    const ushort* apb = A + (size_t)(bm + r) * K + c;    // rows < NP, always in-bounds
    const ushort* bpb = Bt + (size_t)(bn + r) * K + c;

    uint4 a0 = *(const uint4*)(apb);
    uint4 a1 = *(const uint4*)(apb + 8);
    uint4 b0 = *(const uint4*)(bpb);
    uint4 b1 = *(const uint4*)(bpb + 8);

    for (int k0 = 0; k0 < K; k0 += 32) {
        *(uint4*)&As[r * LP + c]     = a0;
        *(uint4*)&As[r * LP + c + 8] = a1;
        *(uint4*)&Bs[r * LP + c]     = b0;
        *(uint4*)&Bs[r * LP + c + 8] = b1;
        __syncthreads();

        // prefetch next K-slab NOW — 64 B/thread in flight under the MFMAs
        int kn = (k0 + 32 < K) ? (k0 + 32) : k0;
        a0 = *(const uint4*)(apb + kn);
        a1 = *(const uint4*)(apb + kn + 8);
        b0 = *(const uint4*)(bpb + kn);
        b1 = *(const uint4*)(bpb + kn + 8);

        short8 afr[4], bfr[4];
#pragma unroll
        for (int i = 0; i < 4; i++)
            afr[i] = *(const short8*)&As[(wm + i * 16 + frow) * LP + kq];
#pragma unroll
        for (int j = 0; j < 4; j++)
            bfr[j] = *(const short8*)&Bs[(wn + j * 16 + frow) * LP + kq];
#pragma unroll
        for (int i = 0; i < 4; i++)
#pragma unroll
            for (int j = 0; j < 4; j++)
                acc[i][j] = __builtin_amdgcn_mfma_f32_16x16x32_bf16(afr[i], bfr[j], acc[i][j], 0, 0, 0);

        __syncthreads();
    }

    // ---- C write: row = quad*4+reg, col = lane&15 (verified m89 mapping); C padded to NP rows
    int ccol = bn + wn + frow;
    int crow = bm + wm + (lane >> 4) * 4;
#pragma unroll
    for (int i = 0; i < 4; i++) {
#pragma unroll
        for (int reg = 0; reg < 4; reg++) {
            int row = crow + i * 16 + reg;
#pragma unroll
            for (int j = 0; j < 4; j++)
                C[(size_t)row * N + ccol + j * 16] = f2b(acc[i][j][reg]);
        }
    }

    // ---- fused attention scores: this wave's 64 cols lie in exactly one head
    int Cc = N / H;
    int hd = (bn + wn) / Cc;
    float avs[4], avd[4];
#pragma unroll
    for (int j = 0; j < 4; j++) {
        avs[j] = a_s[bn + wn + frow + j * 16];
        avd[j] = a_d[bn + wn + frow + j * 16];
    }
#pragma unroll
    for (int i = 0; i < 4; i++) {
#pragma unroll
        for (int reg = 0; reg < 4; reg++) {
            float ps = 0.f, pd = 0.f;
#pragma unroll
            for (int j = 0; j < 4; j++) {
                float v = acc[i][j][reg];
                ps += v * avs[j];
                pd += v * avd[j];
            }
#pragma unroll
            for (int off = 1; off < 16; off <<= 1) {
                ps += __shfl_xor(ps, off, 64);
                pd += __shfl_xor(pd, off, 64);
            }
            int row = crow + i * 16 + reg;
            if ((lane & 15) == 0 && row < NN) {
                atomicAdd(&als[row * H + hd], ps);
                atomicAdd(&ald[row * H + hd], pd);
            }
        }
    }
}

// ---------------------------------------------------------------- CSR aggregation
// ONE WAVE PER DST NODE, all heads together.
template <int H, int HC, bool ELU_ACT, bool OUT_BF16>
__global__ __launch_bounds__(256) void aggregate(const ushort* __restrict__ hlin,
                                                 const float* __restrict__ als,
                                                 const float* __restrict__ ald,
                                                 const int* __restrict__ row_ptr,
                                                 const int* __restrict__ col,
                                                 const float* __restrict__ bias,
                                                 void* __restrict__ outv) {
    constexpr int CP = HC / 64;       // channels per lane (4 or 2)
    constexpr int GS = 64 / H;        // lanes per head group (16 or 64)
    int wv = threadIdx.x >> 6, lane = threadIdx.x & 63;
    int dst = blockIdx.x * 4 + wv;
    if (dst >= NN) return;
    int rs = row_ptr[dst], re = row_ptr[dst + 1];
    int deg = re - rs;
    int eg = lane & (GS - 1);
    int head = lane / GS;
    float ad = ald[dst * H + head];

    float acc[CP];
#pragma unroll
    for (int j = 0; j < CP; j++) acc[j] = 0.f;

    uint laneoff = (uint)(lane * CP);

    if (deg <= GS) {
        int src = 0;
        float s = -1e30f;
        if (eg < deg) {
            src = col[rs + eg];
            float sc = als[src * H + head] + ad;
            s = sc > 0.f ? sc : SLOPE * sc;
        }
        float m = s;
#pragma unroll
        for (int off = 1; off < GS; off <<= 1) m = fmaxf(m, __shfl_xor(m, off, 64));
        float e = (eg < deg) ? __expf(s - m) : 0.f;
        float sum = e;
#pragma unroll
        for (int off = 1; off < GS; off <<= 1) sum += __shfl_xor(sum, off, 64);
        float w = e * (1.0f / (sum + 1e-16f));

        int hbase = head * GS;
        int d = 0;
        for (; d + 4 <= deg; d += 4) {
            int s0 = __shfl(src, d, 64),     s1 = __shfl(src, d + 1, 64);
            int s2 = __shfl(src, d + 2, 64), s3 = __shfl(src, d + 3, 64);
            float w0 = __shfl(w, hbase + d, 64),     w1 = __shfl(w, hbase + d + 1, 64);
            float w2 = __shfl(w, hbase + d + 2, 64), w3 = __shfl(w, hbase + d + 3, 64);
            const uint* p0 = (const uint*)(hlin + (uint)s0 * HC + laneoff);
            const uint* p1 = (const uint*)(hlin + (uint)s1 * HC + laneoff);
            const uint* p2 = (const uint*)(hlin + (uint)s2 * HC + laneoff);
            const uint* p3 = (const uint*)(hlin + (uint)s3 * HC + laneoff);
            uint u0[CP / 2], u1[CP / 2], u2[CP / 2], u3[CP / 2];
#pragma unroll
            for (int q = 0; q < CP / 2; q++) { u0[q] = p0[q]; u1[q] = p1[q]; u2[q] = p2[q]; u3[q] = p3[q]; }
#pragma unroll
            for (int q = 0; q < CP / 2; q++) {
                acc[2*q]   += w0 * b2f((ushort)(u0[q] & 0xffff)) + w1 * b2f((ushort)(u1[q] & 0xffff))
                            + w2 * b2f((ushort)(u2[q] & 0xffff)) + w3 * b2f((ushort)(u3[q] & 0xffff));
                acc[2*q+1] += w0 * b2f((ushort)(u0[q] >> 16)) + w1 * b2f((ushort)(u1[q] >> 16))
                            + w2 * b2f((ushort)(u2[q] >> 16)) + w3 * b2f((ushort)(u3[q] >> 16));
            }
        }
        for (; d < deg; d++) {
            int sd = __shfl(src, d, 64);
            float wd = __shfl(w, hbase + d, 64);
            const uint* p = (const uint*)(hlin + (uint)sd * HC + laneoff);
#pragma unroll
            for (int q = 0; q < CP / 2; q++) {
                uint u = p[q];
                acc[2*q]   += wd * b2f((ushort)(u & 0xffff));
                acc[2*q+1] += wd * b2f((ushort)(u >> 16));
            }
        }
    } else {
        float m = -1e30f;
        for (int e2 = eg; e2 < deg; e2 += GS) {
            int sc0 = col[rs + e2];
            float sc = als[sc0 * H + head] + ad;
            sc = sc > 0.f ? sc : SLOPE * sc;
            m = fmaxf(m, sc);
        }
#pragma unroll
        for (int off = 1; off < GS; off <<= 1) m = fmaxf(m, __shfl_xor(m, off, 64));
        float sum = 0.f;
        for (int e2 = eg; e2 < deg; e2 += GS) {
            int sc0 = col[rs + e2];
            float sc = als[sc0 * H + head] + ad;
            sc = sc > 0.f ? sc : SLOPE * sc;
            sum += __expf(sc - m);
        }
#pragma unroll
        for (int off = 1; off < GS; off <<= 1) sum += __shfl_xor(sum, off, 64);
        float inv = 1.0f / (sum + 1e-16f);
        for (int d = 0; d < deg; d++) {
            int sd = col[rs + d];
            float sc = als[sd * H + head] + ad;
            sc = sc > 0.f ? sc : SLOPE * sc;
            float wd = __expf(sc - m) * inv;
            const uint* p = (const uint*)(hlin + (uint)sd * HC + laneoff);
#pragma unroll
            for (int q = 0; q < CP / 2; q++) {
                uint u = p[q];
                acc[2*q]   += wd * b2f((ushort)(u & 0xffff));
                acc[2*q+1] += wd * b2f((ushort)(u >> 16));
            }
        }
    }

#pragma unroll
    for (int j = 0; j < CP; j++) {
        float v = acc[j] + bias[lane * CP + j];
        if (ELU_ACT) v = v > 0.f ? v : (__expf(v) - 1.0f);
        acc[j] = v;
    }
    if (OUT_BF16) {
        ushort* outp = (ushort*)outv + (size_t)dst * HC + laneoff;
        uint pk[CP / 2];
#pragma unroll
        for (int q = 0; q < CP / 2; q++)
            pk[q] = (uint)f2b(acc[2*q]) | ((uint)f2b(acc[2*q+1]) << 16);
#pragma unroll
        for (int q = 0; q < CP / 2; q++) ((uint*)outp)[q] = pk[q];
    } else {
        float* outp = (float*)outv + (size_t)dst * HC + laneoff;
#pragma unroll
        for (int j = 0; j < CP; j++) outp[j] = acc[j];
    }
}

// ---------------------------------------------------------------- launch
extern "C" void kernel_launch(void* const* d_in, const int* in_sizes, int n_in,
                              void* d_out, int out_size, void* d_ws, size_t ws_size,
                              hipStream_t stream) {
    const float* x   = (const float*)d_in[0];
    const int*   ei  = (const int*)d_in[1];
    const float* W0  = (const float*)d_in[2];
    const float* as0 = (const float*)d_in[3];
    const float* ad0 = (const float*)d_in[4];
    const float* b0  = (const float*)d_in[5];
    const float* W1  = (const float*)d_in[6];
    const float* as1 = (const float*)d_in[7];
    const float* ad1 = (const float*)d_in[8];
    const float* b1  = (const float*)d_in[9];
    const float* W2  = (const float*)d_in[10];
    const float* as2 = (const float*)d_in[11];
    const float* ad2 = (const float*)d_in[12];
    const float* b2  = (const float*)d_in[13];
    float* out = (float*)d_out;

    char* ws = (char*)d_ws;
    size_t off = 0;
    auto alloc = [&](size_t bytes) {
        void* p = ws + off;
        off += (bytes + 255) & ~(size_t)255;
        return p;
    };
    ushort* xb   = (ushort*)alloc((size_t)NP * 128 * 2);   // padded to NP rows
    ushort* h    = (ushort*)alloc((size_t)NP * 256 * 2);
    ushort* actB = (ushort*)alloc((size_t)NP * 256 * 2);
    ushort* actC = (ushort*)alloc((size_t)NP * 256 * 2);
    ushort* Wt0  = (ushort*)alloc((size_t)256 * 128 * 2);
    ushort* Wt1  = (ushort*)alloc((size_t)256 * 256 * 2);
    ushort* Wt2  = (ushort*)alloc((size_t)128 * 256 * 2);
    float* als   = (float*)alloc((size_t)NN * 4 * 4);
    float* ald   = (float*)alloc((size_t)NN * 4 * 4);
    int* deg     = (int*)alloc((size_t)NN * 4);
    int* incl    = (int*)alloc((size_t)NN * 4);
    int* row_ptr = (int*)alloc((size_t)(NN + 1) * 4);
    int* cursor  = (int*)alloc((size_t)NN * 4);
    int* col     = (int*)alloc((size_t)ET * 4);
    int* bsums   = (int*)alloc(128 * 4);

    const int NBLK = (NN + 1023) / 1024;   // 98

    // ---- CSR (shared by all layers)
    hipMemsetAsync(deg, 0, (size_t)NN * 4, stream);
    count_deg<<<(EE + 255) / 256, 256, 0, stream>>>(ei, deg);
    scan1<<<NBLK, 256, 0, stream>>>(deg, incl, bsums);
    scan2<<<1, 128, 0, stream>>>(bsums, NBLK);
    scan3<<<(NN + 255) / 256, 256, 0, stream>>>(incl, deg, bsums, row_ptr, cursor);
    scatter<<<(EE + 255) / 256, 256, 0, stream>>>(ei, cursor, col);
    selfloop<<<(NN + 255) / 256, 256, 0, stream>>>(cursor, col);

    // ---- bf16 conversions
    cast_to_bf16<<<(NN * 128 / 4 + 255) / 256, 256, 0, stream>>>(x, xb, NN * 128 / 4);
    transpose_cast<<<(256 * 128 + 255) / 256, 256, 0, stream>>>(W0, Wt0, 128, 256);
    transpose_cast<<<(256 * 256 + 255) / 256, 256, 0, stream>>>(W1, Wt1, 256, 256);
    transpose_cast<<<(128 * 256 + 255) / 256, 256, 0, stream>>>(W2, Wt2, 256, 128);

    const int GM = NP / 128;           // 782
    const int NB4 = (NN + 3) / 4;      // 25000
    const size_t ALB = (size_t)NN * 4 * 4;

    // ---- layer 0
    hipMemsetAsync(als, 0, ALB, stream);
    hipMemsetAsync(ald, 0, ALB, stream);
    gemm_bf16<<<dim3(GM, 2), 256, 0, stream>>>(xb, Wt0, h, as0, ad0, als, ald, 128, 256, 4);
    aggregate<4, 256, true, true><<<NB4, 256, 0, stream>>>(h, als, ald, row_ptr, col, b0, actB);

    // ---- layer 1
    hipMemsetAsync(als, 0, ALB, stream);
    hipMemsetAsync(ald, 0, ALB, stream);
    gemm_bf16<<<dim3(GM, 2), 256, 0, stream>>>(actB, Wt1, h, as1, ad1, als, ald, 256, 256, 4);
    aggregate<4, 256, true, true><<<NB4, 256, 0, stream>>>(h, als, ald, row_ptr, col, b1, actC);

    // ---- layer 2
    hipMemsetAsync(als, 0, ALB, stream);
    hipMemsetAsync(ald, 0, ALB, stream);
    gemm_bf16<<<dim3(GM, 1), 256, 0, stream>>>(actC, Wt2, h, as2, ad2, als, ald, 256, 128, 1);
    aggregate<1, 128, false, false><<<NB4, 256, 0, stream>>>(h, als, ald, row_ptr, col, b2, out);
}